// Round 2
// baseline (867.851 us; speedup 1.0000x reference)
//
#include <hip/hip_runtime.h>

#define TILE 32
#define HALO 3
#define IN_W 38       // TILE + 2*HALO
#define IN_PITCH 40   // pad to multiple of 4 floats (16B) for ds_read_b128
#define NORI 8
#define KS 7
#define CH 32
#define IMG 224

__global__ __launch_bounds__(256, 4)
void gabor_dw_conv(const float* __restrict__ x, const float* __restrict__ filt,
                   float* __restrict__ out) {
    __shared__ __align__(16) float s_in[IN_W * IN_PITCH];   // 38*40*4 = 6080 B
    __shared__ __align__(16) float s_w[KS * NORI * 8];      // [ky][r][kx pad 8] = 1792 B

    const int tid = threadIdx.x;
    const int tile = blockIdx.x;        // 0..48 (7x7 tiles)
    const int c = blockIdx.y;           // 0..31
    const int b = blockIdx.z;           // 0..15
    const int tbx = tile % 7, tby = tile / 7;
    const int gx0 = tbx * TILE, gy0 = tby * TILE;

    // ---- stage filter taps, re-laid-out as [ky][r][kx(pad 8)] ----
    // 448 slots, 256 threads -> grid-stride; each slot written exactly once.
    for (int i = tid; i < KS * NORI * 8; i += 256) {
        int ky = i >> 6;            // i / 64
        int r  = (i >> 3) & 7;
        int kx = i & 7;
        float v = 0.f;
        if (kx < 7) v = filt[(c * NORI + r) * 49 + ky * 7 + kx];
        s_w[i] = v;
    }

    // ---- stage input tile with halo (zero-fill OOB for SAME padding) ----
    const float* xp = x + (size_t)(b * CH + c) * (IMG * IMG);
    {
        int cc = tid & 63, rr = tid >> 6;   // 64 lanes wide, 4 row-groups
        if (cc < IN_W) {
            int gx = gx0 - HALO + cc;
            bool xin = (gx >= 0) && (gx < IMG);
            for (int row = rr; row < IN_W; row += 4) {
                int gy = gy0 - HALO + row;
                float v = 0.f;
                if (xin && gy >= 0 && gy < IMG) v = xp[gy * IMG + gx];
                s_in[row * IN_PITCH + cc] = v;
            }
        }
    }
    __syncthreads();

    // ---- compute: each thread = 1 row (ty), 4 consecutive x (4*tx..4*tx+3), 8 orientations
    const int tx = tid & 7, ty = tid >> 3;   // tx 0..7, ty 0..31
    float acc[NORI][4];
    #pragma unroll
    for (int r = 0; r < NORI; ++r) {
        #pragma unroll
        for (int p = 0; p < 4; ++p) acc[r][p] = 0.f;
    }

    #pragma unroll
    for (int ky = 0; ky < KS; ++ky) {
        const float4* rowp = (const float4*)&s_in[(ty + ky) * IN_PITCH + 4 * tx];
        float4 i0 = rowp[0], i1 = rowp[1], i2 = rowp[2];   // 3x ds_read_b128, 16B lane stride
        float in[12] = {i0.x, i0.y, i0.z, i0.w, i1.x, i1.y, i1.z, i1.w,
                        i2.x, i2.y, i2.z, i2.w};
        #pragma unroll
        for (int r = 0; r < NORI; ++r) {
            const float4* wp = (const float4*)&s_w[(ky * NORI + r) * 8];
            float4 wa = wp[0], wb = wp[1];   // uniform addr -> LDS broadcast, conflict-free
            #pragma unroll
            for (int p = 0; p < 4; ++p) {
                acc[r][p] += in[p + 0] * wa.x + in[p + 1] * wa.y + in[p + 2] * wa.z
                           + in[p + 3] * wa.w + in[p + 4] * wb.x + in[p + 5] * wb.y
                           + in[p + 6] * wb.z;
            }
        }
    }

    // ---- coalesced float4 stores ----
    const int oy = gy0 + ty;
    const int ox = gx0 + 4 * tx;
    #pragma unroll
    for (int r = 0; r < NORI; ++r) {
        float4 v = make_float4(acc[r][0], acc[r][1], acc[r][2], acc[r][3]);
        size_t off = ((size_t)(b * (CH * NORI) + c * NORI + r) * IMG + oy) * IMG + ox;
        *(float4*)(out + off) = v;
    }
}

extern "C" void kernel_launch(void* const* d_in, const int* in_sizes, int n_in,
                              void* d_out, int out_size, void* d_ws, size_t ws_size,
                              hipStream_t stream) {
    const float* x = (const float*)d_in[0];
    const float* filt = (const float*)d_in[1];
    float* out = (float*)d_out;

    dim3 grid(49, CH, 16);   // (7x7 tiles, channels, batch)
    dim3 block(256);
    gabor_dw_conv<<<grid, block, 0, stream>>>(x, filt, out);
}